// Round 7
// baseline (247.925 us; speedup 1.0000x reference)
//
#include <hip/hip_runtime.h>
#include <hip/hip_bf16.h>
#include <stdint.h>
#include <stddef.h>

typedef __attribute__((ext_vector_type(4))) float f32x4;
typedef _Float16 f16x8 __attribute__((ext_vector_type(8)));

#define BN 128
// coarse scores are in 2^20-scaled units: sc = 2^20*(||e||^2 - 2 z.e) + eps.
// margin = (np grid ~6e-5 + >>8 sigma of fp16 coarse error ~6.4e-6) * 2^20
#define MARGIN 230.0f

// norm table in module-static device memory (ws_size may be exactly 512 KB).
__device__ float g_embn[1024];

// A-tile slot swizzle: even bank spread on stage-A write + af read.
__device__ __forceinline__ int swzA(int n) { return (n ^ (n >> 3)) & 7; }

// ---------------------------------------------------------------------------
// prep (verbatim from r3, correctness-proven): embf = fp16(e*1024) in
// FRAGMENT-MAJOR layout
//   embf[((kt*8+ds)*2+wc)*4+j][lane l=q*16+c][e] = e'[kt*128+wc*64+j*16+c][ds*32+q*8+e]
// so a wave's MFMA B-fragment load is one coalesced 1KB global_load_dwordx4
// with a per-thread CONSTANT address (+8192B per phase, j*1024 as imm offset).
// Also g_embn[code] = 2^20*||e'||^2 (fp16-rounded values -> MFMA-consistent).
// ---------------------------------------------------------------------------
__global__ __launch_bounds__(256) void emb_prep_kernel(const float* __restrict__ emb,
                                                       _Float16* __restrict__ embf) {
    int tid  = blockIdx.x * 256 + threadIdx.x;   // 32768 = 1024 codes x 32 groups
    int code = tid >> 5;
    int g8   = tid & 31;                         // 8-dim group
    const float* src = emb + (size_t)code * 256 + g8 * 8;
    f32x4 v0 = *(const f32x4*)src;
    f32x4 v1 = *(const f32x4*)(src + 4);
    f16x8 h;
    float s = 0.f;
#pragma unroll
    for (int j = 0; j < 4; ++j) {
        h[j]     = (_Float16)(v0[j] * 1024.0f);  // *2^10 exact, then RNE cvt
        h[4 + j] = (_Float16)(v1[j] * 1024.0f);
        float a = (float)h[j], b = (float)h[4 + j];
        s = fmaf(a, a, s); s = fmaf(b, b, s);
    }
    // reduce norm over the 32 threads of this code (aligned 32-lane group)
#pragma unroll
    for (int off = 1; off < 32; off <<= 1) s += __shfl_xor(s, off, 64);
    if (g8 == 0) g_embn[code] = s;

    int kt = code >> 7, r = code & 127;
    int wc = r >> 6, j4 = (r >> 4) & 3, c = r & 15;
    int ds = g8 >> 2, q = g8 & 3, l = q * 16 + c;
    size_t off16 = ((((size_t)(kt * 8 + ds) * 2 + wc) * 4 + j4) * 64 + l) * 8;
    *(f16x8*)&embf[off16] = h;
}

// ---------------------------------------------------------------------------
// Fused VQ: barrier-free fp16 MFMA coarse pass. B fragments load DIRECTLY
// from the L1/L2-resident fragment-major embf into the MFMA inputs (no LDS-B,
// no DMA, no register double-buffer -> r2's proven 64-VGPR footprint).
// A tile in LDS, read-only after stage A. Latency hidden by free-running
// waves (no main-loop barriers). Then best-2 + bit-exact numpy-f32 rescore.
// 512 threads / 8 waves: wr = w>>1 (32-row quarter), wc = w&1 (64-code half).
// ---------------------------------------------------------------------------
__global__ __launch_bounds__(512, 4) void vq_kernel(
        const float* __restrict__ z,
        const float* __restrict__ emb,
        const _Float16* __restrict__ embf,
        float* __restrict__ out) {

    __shared__ _Float16 A_sh[BN * 256];   // 64 KB fp16 z tile (reused as cv/ci)
    __shared__ int      W_sh[1410];       // 5.6 KB worklist scratch

    const int t  = threadIdx.x;
    const int w  = t >> 6;   // 0..7
    const int l  = t & 63;
    const int c  = l & 15;   // MFMA N-lane
    const int q  = l >> 4;   // MFMA quad
    const int wr = w >> 1;   // row quarter (32 rows)
    const int wc = w & 1;    // code half  (64 codes)

    const int n0    = blockIdx.x * BN;
    const int b_img = n0 >> 12;
    const int hw0   = n0 & 4095;
    const float* zb = z + (size_t)b_img * (256 * 4096) + hw0;

    // ---- Stage A: z NCHW f32 -> fp16 [n][d], transposed, swizzled ----
#pragma unroll
    for (int it = 0; it < 2; ++it) {
        int task = it * 512 + t;      // 32 nquad x 32 dgroups
        int nq = task & 31;           // lane-contiguous -> 512B coalesced
        int dg = task >> 5;
        const float* g = zb + (size_t)(dg * 8) * 4096 + nq * 4;
        f32x4 col[8];
#pragma unroll
        for (int j = 0; j < 8; ++j) col[j] = *(const f32x4*)(g + (size_t)j * 4096);
#pragma unroll
        for (int u = 0; u < 4; ++u) {
            int n = nq * 4 + u;
            f16x8 v;
#pragma unroll
            for (int j = 0; j < 8; ++j) v[j] = (_Float16)col[j][u];
            *(f16x8*)&A_sh[n * 256 + ((dg ^ swzA(n)) * 8)] = v;
        }
    }
    __syncthreads();   // the ONLY barrier before the epilogue phases

    // per-thread B pointer: phase s chunk at +s*8192, j at imm offset j*1024
    const char* bptr = (const char*)embf + ((size_t)wc << 12) + ((size_t)l << 4);

    f32x4 acc[2][4];
    float v1[8], v2[8];
    int   i1[8], i2[8];
#pragma unroll
    for (int i = 0; i < 2; ++i)
#pragma unroll
        for (int j = 0; j < 4; ++j) acc[i][j] = (f32x4){0.f, 0.f, 0.f, 0.f};
#pragma unroll
    for (int p = 0; p < 8; ++p) { v1[p] = 3.4e38f; v2[p] = 3.4e38f; i1[p] = 0x7fffffff; i2[p] = 0x7fffffff; }

    for (int kt = 0; kt < 8; ++kt) {
        // norm loads early; consumed in the kt epilogue (L1-hot 4KB)
        float en4[4];
#pragma unroll
        for (int j = 0; j < 4; ++j) en4[j] = g_embn[kt * 128 + wc * 64 + j * 16 + c];

#pragma unroll
        for (int ds = 0; ds < 8; ++ds) {
            // B fragments straight from global (L1-hot: 8 waves share the chunk)
            f16x8 bfr[4];
#pragma unroll
            for (int j = 0; j < 4; ++j)
                bfr[j] = *(const f16x8*)(bptr + j * 1024);
            bptr += 8192;

            f16x8 af[2];
#pragma unroll
            for (int i = 0; i < 2; ++i) {
                int n  = wr * 32 + i * 16 + c;
                int pg = ((ds << 2) + q) ^ swzA(n);
                af[i] = *(const f16x8*)&A_sh[n * 256 + pg * 8];
            }
#pragma unroll
            for (int i = 0; i < 2; ++i)
#pragma unroll
                for (int j = 0; j < 4; ++j)
                    acc[i][j] = __builtin_amdgcn_mfma_f32_16x16x32_f16(af[i], bfr[j], acc[i][j], 0, 0, 0);
        }

        // ---- kt epilogue: scale-consistent score, best-2 ----
        // en = 2^20*||e||^2 (precomputed) ; acc = 2^10*(z.e)
        // sc = en - 2048*acc = 2^20*(||e||^2 - 2 z.e)  (argmin-equivalent)
#pragma unroll
        for (int j = 0; j < 4; ++j) {
            float en = en4[j];
            int code = kt * 128 + wc * 64 + j * 16 + c;
#pragma unroll
            for (int i = 0; i < 2; ++i) {
#pragma unroll
                for (int r = 0; r < 4; ++r) {
                    int p = i * 4 + r;
                    float sc = fmaf(-2048.0f, acc[i][j][r], en);
                    if (sc < v1[p]) {
                        v2[p] = v1[p]; i2[p] = i1[p];
                        v1[p] = sc;    i1[p] = code;
                    } else if (sc < v2[p]) {
                        v2[p] = sc;    i2[p] = code;
                    }
                }
            }
        }
#pragma unroll
        for (int i = 0; i < 2; ++i)
#pragma unroll
            for (int j = 0; j < 4; ++j) acc[i][j] = (f32x4){0.f, 0.f, 0.f, 0.f};
    }

    __syncthreads();   // A_sh dead -> reuse as scratch

    // ---- dump best-2 per (lane,row), diagonal-swizzled: entry(slot,row) at
    //      [slot*128 + ((row+slot)&127)] -> scan reads stride-1, writes <=2-way
    float* cv = (float*)A_sh;              // 64 slots x 128 rows (32 KB)
    int*   ci = ((int*)A_sh) + 8192;       // 32 KB
    int* idx_fin = W_sh;                   // 128
    int* wl_n    = W_sh + 128;             // 1
    int* wl_row  = W_sh + 129;             // 128
    int* wl_nc   = W_sh + 257;             // 128
    int* wl_cand = W_sh + 385;             // 128*8

    if (t == 0) wl_n[0] = 0;
#pragma unroll
    for (int p = 0; p < 8; ++p) {
        int row = wr * 32 + (p >> 2) * 16 + q * 4 + (p & 3);
        int s0  = (wc * 16 + c) * 2;
        cv[s0 * 128       + ((row + s0)     & 127)] = v1[p];
        ci[s0 * 128       + ((row + s0)     & 127)] = i1[p];
        cv[(s0 + 1) * 128 + ((row + s0 + 1) & 127)] = v2[p];
        ci[(s0 + 1) * 128 + ((row + s0 + 1) & 127)] = i2[p];
    }
    __syncthreads();

    if (t < BN) {
        float mv = 3.4e38f; int mi = 0x7fffffff;
#pragma unroll 8
        for (int s = 0; s < 64; ++s) {
            float v = cv[s * 128 + ((t + s) & 127)];
            int  id = ci[s * 128 + ((t + s) & 127)];
            if (v < mv || (v == mv && id < mi)) { mv = v; mi = id; }
        }
        int   cand[8]; int nc = 0;
        float thr = mv + MARGIN;
        for (int s = 0; s < 64; ++s) {
            float v = cv[s * 128 + ((t + s) & 127)];
            int  id = ci[s * 128 + ((t + s) & 127)];
            if (v <= thr && id < 1024 && nc < 8) cand[nc++] = id;
        }
        idx_fin[t] = mi;
        if (nc > 1) {
            int slot = atomicAdd(wl_n, 1);
            wl_row[slot] = t;
            wl_nc[slot]  = nc;
            for (int i = 0; i < nc; ++i) wl_cand[slot * 8 + i] = cand[i];
        }
    }
    __syncthreads();

    // ---- wave-cooperative bit-exact numpy-f32 rescore ----
    int nwl = wl_n[0];
    for (int e = w; e < nwl; e += 8) {
        int row = wl_row[e];
        int nc  = wl_nc[e];
        const float* zrow = zb + row;      // element d at zrow[d*4096]

        // a_n: np pairwise sum of z^2, 16 parallel chains (np 8-acc x 2 halves)
        int j  = l & 15, h = j >> 3, jj = j & 7;
        float x0 = zrow[(size_t)(h * 128 + jj) * 4096];
        float r  = __fmul_rn(x0, x0);
        for (int m = 1; m < 16; ++m) {
            float x = zrow[(size_t)(h * 128 + jj + 8 * m) * 4096];
            r = __fadd_rn(r, __fmul_rn(x, x));
        }
        float s1 = __fadd_rn(r,  __shfl_xor(r,  1, 64));
        float s2 = __fadd_rn(s1, __shfl_xor(s1, 2, 64));
        float s4 = __fadd_rn(s2, __shfl_xor(s2, 4, 64));
        float a_n = __fadd_rn(s4, __shfl_xor(s4, 8, 64));
        a_n = __shfl(a_n, 0, 64);

        float best = 3.4e38f; int bid = 0x7fffffff;
        for (int cx = 0; cx < nc; ++cx) {
            int id = wl_cand[e * 8 + cx];
            const float* er = emb + (size_t)id * 256;
            // b_k: same bit-exact np tree, contiguous reads
            float y0 = er[h * 128 + jj];
            float rb = __fmul_rn(y0, y0);
            for (int m = 1; m < 16; ++m) {
                float y = er[h * 128 + jj + 8 * m];
                rb = __fadd_rn(rb, __fmul_rn(y, y));
            }
            float b1 = __fadd_rn(rb, __shfl_xor(rb, 1, 64));
            float b2 = __fadd_rn(b1, __shfl_xor(b1, 2, 64));
            float b4 = __fadd_rn(b2, __shfl_xor(b2, 4, 64));
            float b_k = __fadd_rn(b4, __shfl_xor(b4, 8, 64));
            b_k = __shfl(b_k, 0, 64);
            // c: f64 dot, 64-lane butterfly (order-free, ~exact)
            double cd = 0.0;
#pragma unroll
            for (int u = 0; u < 4; ++u) {
                int d = l + u * 64;
                cd = fma((double)zrow[(size_t)d * 4096], (double)er[d], cd);
            }
#pragma unroll
            for (int off = 1; off < 64; off <<= 1) cd += __shfl_xor(cd, off, 64);
            float c32 = (float)cd;
            float sc  = __fsub_rn(__fadd_rn(a_n, b_k), __fmul_rn(2.0f, c32));
            if (sc < best || (sc == best && id < bid)) { best = sc; bid = id; }
        }
        if (l == 0) idx_fin[row] = bid;
    }
    __syncthreads();

    // ---- final index write + z_q gather ----
    if (t < BN) out[n0 + t] = (float)idx_fin[t];

    // each thread owns one spatial position m (id loaded once) and 16 d4-quads:
    // f32x4 row reads (16B/lane from L2-hot emb) + 4B/lane coalesced stores
    float* zq = out + 65536 + (size_t)b_img * (256 * 4096) + hw0;
    {
        int m   = t & 127;
        int sub = t >> 7;                 // 0..3
        int id  = idx_fin[m];
        const float* er = emb + (size_t)id * 256;
#pragma unroll 4
        for (int it = 0; it < 16; ++it) {
            int d4 = it * 4 + sub;        // 0..63
            f32x4 v = *(const f32x4*)&er[d4 * 4];
#pragma unroll
            for (int jj2 = 0; jj2 < 4; ++jj2)
                zq[(size_t)(d4 * 4 + jj2) * 4096 + m] = v[jj2];
        }
    }
}

// ---------------------------------------------------------------------------
extern "C" void kernel_launch(void* const* d_in, const int* in_sizes, int n_in,
                              void* d_out, int out_size, void* d_ws, size_t ws_size,
                              hipStream_t stream) {
    const float* z   = (const float*)d_in[0];   // f32 [16,256,64,64]
    const float* emb = (const float*)d_in[1];   // f32 [1024,256]
    _Float16* embf = (_Float16*)d_ws;            // 512 KB fragment-major fp16
    float* out = (float*)d_out;

    emb_prep_kernel<<<128, 256, 0, stream>>>(emb, embf);
    vq_kernel<<<65536 / BN, 512, 0, stream>>>(z, emb, embf, out);
}

// Round 8
// 226.670 us; speedup vs baseline: 1.0938x; 1.0938x over previous
//
#include <hip/hip_runtime.h>
#include <hip/hip_bf16.h>
#include <stdint.h>
#include <stddef.h>

typedef __attribute__((ext_vector_type(4))) float f32x4;
typedef _Float16 f16x8 __attribute__((ext_vector_type(8)));

#define BN 128
// coarse scores are in 2^20-scaled units: sc = 2^20*(||e||^2 - 2 z.e) + eps.
// margin = (np grid ~6e-5 + >>8 sigma of fp16 coarse error ~6.4e-6) * 2^20
#define MARGIN 230.0f

// norm table in module-static device memory (ws_size may be exactly 512 KB).
__device__ float g_embn[1024];

// A-tile slot swizzle: even bank spread on stage-A write + af read.
__device__ __forceinline__ int swzA(int n) { return (n ^ (n >> 3)) & 7; }

// ---------------------------------------------------------------------------
// prep (verbatim from r3/r7, correctness-proven): embf = fp16(e*1024) in
// FRAGMENT-MAJOR layout
//   embf[((kt*8+ds)*2+wc)*4+j][lane l=q*16+c][e] = e'[kt*128+wc*64+j*16+c][ds*32+q*8+e]
// so a wave's MFMA B-fragment load is one coalesced 1KB global_load_dwordx4
// with a per-thread CONSTANT address (+8192B per phase, j*1024 as imm offset).
// Also g_embn[code] = 2^20*||e'||^2 (fp16-rounded values -> MFMA-consistent).
// ---------------------------------------------------------------------------
__global__ __launch_bounds__(256) void emb_prep_kernel(const float* __restrict__ emb,
                                                       _Float16* __restrict__ embf) {
    int tid  = blockIdx.x * 256 + threadIdx.x;   // 32768 = 1024 codes x 32 groups
    int code = tid >> 5;
    int g8   = tid & 31;                         // 8-dim group
    const float* src = emb + (size_t)code * 256 + g8 * 8;
    f32x4 v0 = *(const f32x4*)src;
    f32x4 v1 = *(const f32x4*)(src + 4);
    f16x8 h;
    float s = 0.f;
#pragma unroll
    for (int j = 0; j < 4; ++j) {
        h[j]     = (_Float16)(v0[j] * 1024.0f);  // *2^10 exact, then RNE cvt
        h[4 + j] = (_Float16)(v1[j] * 1024.0f);
        float a = (float)h[j], b = (float)h[4 + j];
        s = fmaf(a, a, s); s = fmaf(b, b, s);
    }
    // reduce norm over the 32 threads of this code (aligned 32-lane group)
#pragma unroll
    for (int off = 1; off < 32; off <<= 1) s += __shfl_xor(s, off, 64);
    if (g8 == 0) g_embn[code] = s;

    int kt = code >> 7, r = code & 127;
    int wc = r >> 6, j4 = (r >> 4) & 3, c = r & 15;
    int ds = g8 >> 2, q = g8 & 3, l = q * 16 + c;
    size_t off16 = ((((size_t)(kt * 8 + ds) * 2 + wc) * 4 + j4) * 64 + l) * 8;
    *(f16x8*)&embf[off16] = h;
}

// ---------------------------------------------------------------------------
// Fused VQ: barrier-free fp16 MFMA coarse pass, B direct from fragment-major
// embf with EXPLICIT 1-phase-ahead prefetch into ping/pong register sets
// (pa*/pb*, all names static -> no scratch). 1024 thr / 16 waves, per-wave
// state halved (16 rows, acc[4]) so pipeline fits the 128-VGPR cap.
// A tile in LDS, read-only after stage A. No main-loop barriers: per-wave
// load latency hidden by the prefetch distance + 4 waves/SIMD TLP.
// wr = w>>1 (16-row octet), wc = w&1 (64-code half).
// ---------------------------------------------------------------------------
__global__ __launch_bounds__(1024, 4) void vq_kernel(
        const float* __restrict__ z,
        const float* __restrict__ emb,
        const _Float16* __restrict__ embf,
        float* __restrict__ out) {

    __shared__ _Float16 A_sh[BN * 256];   // 64 KB fp16 z tile (reused as cv/ci)
    __shared__ int      W_sh[1410];       // 5.6 KB worklist scratch

    const int t  = threadIdx.x;
    const int w  = t >> 6;   // 0..15
    const int l  = t & 63;
    const int c  = l & 15;   // MFMA N-lane
    const int q  = l >> 4;   // MFMA quad
    const int wr = w >> 1;   // row octet (16 rows)
    const int wc = w & 1;    // code half (64 codes)

    const int n0    = blockIdx.x * BN;
    const int b_img = n0 >> 12;
    const int hw0   = n0 & 4095;
    const float* zb = z + (size_t)b_img * (256 * 4096) + hw0;

    // ---- Stage A: z NCHW f32 -> fp16 [n][d], transposed, swizzled ----
    {
        int nq = t & 31;              // lane-contiguous -> 512B coalesced
        int dg = t >> 5;              // 0..31
        const float* g = zb + (size_t)(dg * 8) * 4096 + nq * 4;
        f32x4 col[8];
#pragma unroll
        for (int j = 0; j < 8; ++j) col[j] = *(const f32x4*)(g + (size_t)j * 4096);
#pragma unroll
        for (int u = 0; u < 4; ++u) {
            int n = nq * 4 + u;
            f16x8 v;
#pragma unroll
            for (int j = 0; j < 8; ++j) v[j] = (_Float16)col[j][u];
            *(f16x8*)&A_sh[n * 256 + ((dg ^ swzA(n)) * 8)] = v;
        }
    }
    __syncthreads();   // the ONLY barrier before the epilogue phases

    // per-thread B pointer: phase s chunk at +s*8192B, j at imm offset j*1024B
    const char* bbase = (const char*)embf + ((size_t)wc << 12) + ((size_t)l << 4);

    f32x4 acc[4];
    float v1[4], v2[4];
    int   i1[4], i2[4];
#pragma unroll
    for (int j = 0; j < 4; ++j) acc[j] = (f32x4){0.f, 0.f, 0.f, 0.f};
#pragma unroll
    for (int p = 0; p < 4; ++p) { v1[p] = 3.4e38f; v2[p] = 3.4e38f; i1[p] = 0x7fffffff; i2[p] = 0x7fffffff; }

    // pipeline prologue: set PA <- chunk 0
    f16x8 pa0 = *(const f16x8*)(bbase);
    f16x8 pa1 = *(const f16x8*)(bbase + 1024);
    f16x8 pa2 = *(const f16x8*)(bbase + 2048);
    f16x8 pa3 = *(const f16x8*)(bbase + 3072);
    f16x8 pb0, pb1, pb2, pb3;

    const int nA = wr * 16 + c;          // this wave's single A-row base
    const int sA = swzA(nA);

    for (int kt = 0; kt < 8; ++kt) {
        // norm loads early; consumed in the kt epilogue (L1-hot 4KB)
        float en4[4];
#pragma unroll
        for (int j = 0; j < 4; ++j) en4[j] = g_embn[kt * 128 + wc * 64 + j * 16 + c];

        const char* bs = bbase + (size_t)kt * 65536;
        // clamped offset for the very last prefetch slot (kt=7,ds=7 -> s=63 dummy)
        const size_t nxt8 = (kt == 7) ? (size_t)7 * 8192 : (size_t)8 * 8192;

#pragma unroll
        for (int ds = 0; ds < 8; ++ds) {
            // 1) prefetch chunk s+1 into the OTHER register set (issue first)
            const char* np = (ds < 7) ? (bs + (size_t)(ds + 1) * 8192) : (bs + nxt8);
            if ((ds & 1) == 0) {
                pb0 = *(const f16x8*)(np);
                pb1 = *(const f16x8*)(np + 1024);
                pb2 = *(const f16x8*)(np + 2048);
                pb3 = *(const f16x8*)(np + 3072);
            } else {
                pa0 = *(const f16x8*)(np);
                pa1 = *(const f16x8*)(np + 1024);
                pa2 = *(const f16x8*)(np + 2048);
                pa3 = *(const f16x8*)(np + 3072);
            }
            // 2) A fragment (LDS, immutable, swizzled; ds compile-time)
            int pg = ((ds << 2) + q) ^ sA;
            f16x8 af = *(const f16x8*)&A_sh[nA * 256 + pg * 8];
            // 3) MFMAs on the CURRENT set (loaded one phase ago)
            if ((ds & 1) == 0) {
                acc[0] = __builtin_amdgcn_mfma_f32_16x16x32_f16(af, pa0, acc[0], 0, 0, 0);
                acc[1] = __builtin_amdgcn_mfma_f32_16x16x32_f16(af, pa1, acc[1], 0, 0, 0);
                acc[2] = __builtin_amdgcn_mfma_f32_16x16x32_f16(af, pa2, acc[2], 0, 0, 0);
                acc[3] = __builtin_amdgcn_mfma_f32_16x16x32_f16(af, pa3, acc[3], 0, 0, 0);
            } else {
                acc[0] = __builtin_amdgcn_mfma_f32_16x16x32_f16(af, pb0, acc[0], 0, 0, 0);
                acc[1] = __builtin_amdgcn_mfma_f32_16x16x32_f16(af, pb1, acc[1], 0, 0, 0);
                acc[2] = __builtin_amdgcn_mfma_f32_16x16x32_f16(af, pb2, acc[2], 0, 0, 0);
                acc[3] = __builtin_amdgcn_mfma_f32_16x16x32_f16(af, pb3, acc[3], 0, 0, 0);
            }
        }

        // ---- kt epilogue: scale-consistent score, best-2 ----
        // en = 2^20*||e||^2 (precomputed) ; acc = 2^10*(z.e)
        // sc = en - 2048*acc = 2^20*(||e||^2 - 2 z.e)  (argmin-equivalent)
#pragma unroll
        for (int j = 0; j < 4; ++j) {
            float en = en4[j];
            int code = kt * 128 + wc * 64 + j * 16 + c;
#pragma unroll
            for (int r = 0; r < 4; ++r) {
                float sc = fmaf(-2048.0f, acc[j][r], en);
                if (sc < v1[r]) {
                    v2[r] = v1[r]; i2[r] = i1[r];
                    v1[r] = sc;    i1[r] = code;
                } else if (sc < v2[r]) {
                    v2[r] = sc;    i2[r] = code;
                }
            }
        }
#pragma unroll
        for (int j = 0; j < 4; ++j) acc[j] = (f32x4){0.f, 0.f, 0.f, 0.f};
    }

    __syncthreads();   // A_sh dead -> reuse as scratch

    // ---- dump best-2 per (lane,row), diagonal-swizzled: entry(slot,row) at
    //      [slot*128 + ((row+slot)&127)] -> scan reads stride-1, writes <=2-way
    float* cv = (float*)A_sh;              // 64 slots x 128 rows (32 KB)
    int*   ci = ((int*)A_sh) + 8192;       // 32 KB
    int* idx_fin = W_sh;                   // 128
    int* wl_n    = W_sh + 128;             // 1
    int* wl_row  = W_sh + 129;             // 128
    int* wl_nc   = W_sh + 257;             // 128
    int* wl_cand = W_sh + 385;             // 128*8

    if (t == 0) wl_n[0] = 0;
#pragma unroll
    for (int p = 0; p < 4; ++p) {
        int row = wr * 16 + q * 4 + p;
        int s0  = (wc * 16 + c) * 2;
        cv[s0 * 128       + ((row + s0)     & 127)] = v1[p];
        ci[s0 * 128       + ((row + s0)     & 127)] = i1[p];
        cv[(s0 + 1) * 128 + ((row + s0 + 1) & 127)] = v2[p];
        ci[(s0 + 1) * 128 + ((row + s0 + 1) & 127)] = i2[p];
    }
    __syncthreads();

    if (t < BN) {
        float mv = 3.4e38f; int mi = 0x7fffffff;
#pragma unroll 8
        for (int s = 0; s < 64; ++s) {
            float v = cv[s * 128 + ((t + s) & 127)];
            int  id = ci[s * 128 + ((t + s) & 127)];
            if (v < mv || (v == mv && id < mi)) { mv = v; mi = id; }
        }
        int   cand[8]; int nc = 0;
        float thr = mv + MARGIN;
        for (int s = 0; s < 64; ++s) {
            float v = cv[s * 128 + ((t + s) & 127)];
            int  id = ci[s * 128 + ((t + s) & 127)];
            if (v <= thr && id < 1024 && nc < 8) cand[nc++] = id;
        }
        idx_fin[t] = mi;
        if (nc > 1) {
            int slot = atomicAdd(wl_n, 1);
            wl_row[slot] = t;
            wl_nc[slot]  = nc;
            for (int i = 0; i < nc; ++i) wl_cand[slot * 8 + i] = cand[i];
        }
    }
    __syncthreads();

    // ---- wave-cooperative bit-exact numpy-f32 rescore ----
    int nwl = wl_n[0];
    for (int e = w; e < nwl; e += 16) {
        int row = wl_row[e];
        int nc  = wl_nc[e];
        const float* zrow = zb + row;      // element d at zrow[d*4096]

        // a_n: np pairwise sum of z^2, 16 parallel chains (np 8-acc x 2 halves)
        int j  = l & 15, h = j >> 3, jj = j & 7;
        float x0 = zrow[(size_t)(h * 128 + jj) * 4096];
        float r  = __fmul_rn(x0, x0);
        for (int m = 1; m < 16; ++m) {
            float x = zrow[(size_t)(h * 128 + jj + 8 * m) * 4096];
            r = __fadd_rn(r, __fmul_rn(x, x));
        }
        float s1 = __fadd_rn(r,  __shfl_xor(r,  1, 64));
        float s2 = __fadd_rn(s1, __shfl_xor(s1, 2, 64));
        float s4 = __fadd_rn(s2, __shfl_xor(s2, 4, 64));
        float a_n = __fadd_rn(s4, __shfl_xor(s4, 8, 64));
        a_n = __shfl(a_n, 0, 64);

        float best = 3.4e38f; int bid = 0x7fffffff;
        for (int cx = 0; cx < nc; ++cx) {
            int id = wl_cand[e * 8 + cx];
            const float* er = emb + (size_t)id * 256;
            // b_k: same bit-exact np tree, contiguous reads
            float y0 = er[h * 128 + jj];
            float rb = __fmul_rn(y0, y0);
            for (int m = 1; m < 16; ++m) {
                float y = er[h * 128 + jj + 8 * m];
                rb = __fadd_rn(rb, __fmul_rn(y, y));
            }
            float b1 = __fadd_rn(rb, __shfl_xor(rb, 1, 64));
            float b2 = __fadd_rn(b1, __shfl_xor(b1, 2, 64));
            float b4 = __fadd_rn(b2, __shfl_xor(b2, 4, 64));
            float b_k = __fadd_rn(b4, __shfl_xor(b4, 8, 64));
            b_k = __shfl(b_k, 0, 64);
            // c: f64 dot, 64-lane butterfly (order-free, ~exact)
            double cd = 0.0;
#pragma unroll
            for (int u = 0; u < 4; ++u) {
                int d = l + u * 64;
                cd = fma((double)zrow[(size_t)d * 4096], (double)er[d], cd);
            }
#pragma unroll
            for (int off = 1; off < 64; off <<= 1) cd += __shfl_xor(cd, off, 64);
            float c32 = (float)cd;
            float sc  = __fsub_rn(__fadd_rn(a_n, b_k), __fmul_rn(2.0f, c32));
            if (sc < best || (sc == best && id < bid)) { best = sc; bid = id; }
        }
        if (l == 0) idx_fin[row] = bid;
    }
    __syncthreads();

    // ---- final index write + z_q gather ----
    if (t < BN) out[n0 + t] = (float)idx_fin[t];

    // each thread owns one spatial position m (id loaded once) and 8 d4-quads:
    // f32x4 row reads (16B/lane from L2-hot emb) + 4B/lane coalesced stores
    float* zq = out + 65536 + (size_t)b_img * (256 * 4096) + hw0;
    {
        int m   = t & 127;
        int sub = t >> 7;                 // 0..7
        int id  = idx_fin[m];
        const float* er = emb + (size_t)id * 256;
#pragma unroll
        for (int it = 0; it < 8; ++it) {
            int d4 = it * 8 + sub;        // 0..63
            f32x4 v = *(const f32x4*)&er[d4 * 4];
#pragma unroll
            for (int jj2 = 0; jj2 < 4; ++jj2)
                zq[(size_t)(d4 * 4 + jj2) * 4096 + m] = v[jj2];
        }
    }
}

// ---------------------------------------------------------------------------
extern "C" void kernel_launch(void* const* d_in, const int* in_sizes, int n_in,
                              void* d_out, int out_size, void* d_ws, size_t ws_size,
                              hipStream_t stream) {
    const float* z   = (const float*)d_in[0];   // f32 [16,256,64,64]
    const float* emb = (const float*)d_in[1];   // f32 [1024,256]
    _Float16* embf = (_Float16*)d_ws;            // 512 KB fragment-major fp16
    float* out = (float*)d_out;

    emb_prep_kernel<<<128, 256, 0, stream>>>(emb, embf);
    vq_kernel<<<65536 / BN, 1024, 0, stream>>>(z, emb, embf, out);
}

// Round 9
// 213.269 us; speedup vs baseline: 1.1625x; 1.0628x over previous
//
#include <hip/hip_runtime.h>
#include <hip/hip_bf16.h>
#include <stdint.h>
#include <stddef.h>

typedef __attribute__((ext_vector_type(4))) float f32x4;
typedef __attribute__((ext_vector_type(16))) float f32x16;
typedef _Float16 f16x8 __attribute__((ext_vector_type(8)));

#define BN 128
// coarse scores are in 2^20-scaled units: sc = 2^20*(||e||^2 - 2 z.e) + eps.
// margin = (np grid ~6e-5 + >>8 sigma of fp16 coarse error ~6.4e-6) * 2^20
// (+ <=0.05 from f16 storage of the folded norm slice)
#define MARGIN 230.0f

// en-slice A-fragments: 32 tiles x 64 lanes x 8 f16 = 32 KB, module-static.
// A[m][k] = (k==0) ? -||e'[m]||^2/2048 : 0  -> one extra MFMA adds the norm
// term into every acc column: sc = -2048*acc = en - 2048*dot exactly.
__device__ _Float16 g_enfrag[32 * 64 * 8];

// ---------------------------------------------------------------------------
// prep: embf = fp16(e*1024) in 32x32x16-A fragment-major layout:
//   embf[((ct*16+ks)*64 + l)*8 + e] = e'[ct*32 + (l&31)][ks*16 + (l>>5)*8 + e]
// (k = (lane>>5)*8+e is the same input mapping family the r4 16x16x32 kernel
//  verified on-harness). Also writes the en-slice frag + zero-fill.
// ---------------------------------------------------------------------------
__global__ __launch_bounds__(256) void emb_prep_kernel(const float* __restrict__ emb,
                                                       _Float16* __restrict__ embf) {
    int tid  = blockIdx.x * 256 + threadIdx.x;   // 32768 = 1024 codes x 32 groups
    // zero-fill en-frag slots not owned by the per-code writers (disjoint)
    if (tid < 16384) {
        int e = tid & 7, lslot = (tid >> 3) & 63;
        if (!(e == 0 && lslot < 32)) g_enfrag[tid] = (_Float16)0.0f;
    }
    int code = tid >> 5;
    int g8   = tid & 31;                         // 8-dim group
    const float* src = emb + (size_t)code * 256 + g8 * 8;
    f32x4 v0 = *(const f32x4*)src;
    f32x4 v1 = *(const f32x4*)(src + 4);
    f16x8 h;
    float s = 0.f;
#pragma unroll
    for (int j = 0; j < 4; ++j) {
        h[j]     = (_Float16)(v0[j] * 1024.0f);  // *2^10 exact, then RNE cvt
        h[4 + j] = (_Float16)(v1[j] * 1024.0f);
        float a = (float)h[j], b = (float)h[4 + j];
        s = fmaf(a, a, s); s = fmaf(b, b, s);
    }
    // reduce ||e'||^2 over the 32 threads of this code (aligned 32-lane group)
#pragma unroll
    for (int off = 1; off < 32; off <<= 1) s += __shfl_xor(s, off, 64);
    int ct = code >> 5, m = code & 31;
    if (g8 == 0) g_enfrag[(ct * 64 + m) * 8] = (_Float16)(-s / 2048.0f);

    int ks = g8 >> 1, hi = g8 & 1;               // dims g8*8+j = ks*16 + hi*8 + j
    size_t off16 = (((size_t)(ct * 16 + ks)) * 64 + hi * 32 + m) * 8;
    *(f16x8*)&embf[off16] = h;
}

// ---------------------------------------------------------------------------
// Fused VQ, transposed 32x32x16 orientation: A = codes (streamed from
// fragment-major embf, per-thread constant addresses, L1-shared), B = z
// (ENTIRE wave slab of 32 rows x 256 dims held in 64 VGPR). Zero main-loop
// LDS / barriers / DMA. Per lane: C col = one z-row, 16 regs = 16 codes ->
// best-2 reduction is register-local (4 buckets). Norm folded via 17th
// K-slice MFMA. Then 32-slot scan + worklist + bit-exact numpy-f32 rescore
// (verbatim from the passing r4 kernel) + z_q gather.
// 512 thr / 8 waves: rg = w>>1 (32-row group), wc = w&1 (512-code half).
// ---------------------------------------------------------------------------
__global__ __launch_bounds__(512, 4) void vq_kernel(
        const float* __restrict__ z,
        const float* __restrict__ emb,
        const _Float16* __restrict__ embf,
        float* __restrict__ out) {

    __shared__ float cv_sh[32 * 128];     // 16 KB best-2 dump (values)
    __shared__ int   ci_sh[32 * 128];     // 16 KB best-2 dump (ids)
    __shared__ int   W_sh[1410];          // 5.6 KB worklist scratch

    const int t  = threadIdx.x;
    const int w  = t >> 6;   // 0..7
    const int l  = t & 63;
    const int ln = l & 31;   // MFMA 32-col lane (z-row within group)
    const int hi = l >> 5;   // k-half / code-subset selector
    const int rg = w >> 1;   // row group (32 rows)
    const int wc = w & 1;    // code half (512 codes = 16 tiles)

    const int n0    = blockIdx.x * BN;
    const int b_img = n0 >> 12;
    const int hw0   = n0 & 4095;
    const float* zb = z + (size_t)b_img * (256 * 4096) + hw0;

    // ---- stage: this wave's z slab straight into registers (fp16) ----
    // lane ln holds row rg*32+ln; dims k = ks*16 + hi*8 + e (B-frag layout).
    const float* zcol = zb + rg * 32 + ln;
    f16x8 zfrag[16];
#pragma unroll
    for (int ks = 0; ks < 16; ++ks) {
        f16x8 v;
#pragma unroll
        for (int e = 0; e < 8; ++e)
            v[e] = (_Float16)zcol[(size_t)(ks * 16 + hi * 8 + e) * 4096];
        zfrag[ks] = v;
    }
    // ones-frag for the en slice: B[k==0][n] = 1
    f16x8 zones;
#pragma unroll
    for (int e = 0; e < 8; ++e) zones[e] = (_Float16)0.0f;
    zones[0] = (_Float16)(hi == 0 ? 1.0f : 0.0f);

    float v1[4], v2[4];
    int   i1[4], i2[4];
#pragma unroll
    for (int p = 0; p < 4; ++p) { v1[p] = 3.4e38f; v2[p] = 3.4e38f; i1[p] = 0x7fffffff; i2[p] = 0x7fffffff; }

    // per-thread constant fragment addresses
    const _Float16* cbase = embf + ((size_t)(wc * 16) * 16 + 0) * 512 + l * 8;
    const _Float16* ebase = &g_enfrag[(wc * 16) * 512 + l * 8];

    for (int ct = 0; ct < 16; ++ct) {
        const _Float16* cp = cbase + (size_t)ct * 8192;   // 16 slices x 512 f16
        f32x16 acc;
#pragma unroll
        for (int r = 0; r < 16; ++r) acc[r] = 0.0f;
#pragma unroll
        for (int ks = 0; ks < 16; ++ks) {
            f16x8 cf = *(const f16x8*)(cp + ks * 512);
            acc = __builtin_amdgcn_mfma_f32_32x32x16_f16(cf, zfrag[ks], acc, 0, 0, 0);
        }
        {   // norm slice: acc[r] += -en[code_r]/2048
            f16x8 ef = *(const f16x8*)(ebase + (size_t)ct * 512);
            acc = __builtin_amdgcn_mfma_f32_32x32x16_f16(ef, zones, acc, 0, 0, 0);
        }
        // ---- tile epilogue: sc = -2048*acc = en - 2048*dot; best-2/bucket ----
        int code0 = (wc * 16 + ct) * 32 + 4 * hi;
#pragma unroll
        for (int r = 0; r < 16; ++r) {
            float sc = -2048.0f * acc[r];
            int code = code0 + (r & 3) + ((r >> 2) << 3);  // C row mapping (m74/m101)
            const int b = r & 3;
            if (sc < v1[b]) {
                v2[b] = v1[b]; i2[b] = i1[b];
                v1[b] = sc;    i1[b] = code;
            } else if (sc < v2[b]) {
                v2[b] = sc;    i2[b] = code;
            }
        }
    }

    // ---- dump best-2: 32 slots x 128 rows, diagonal-swizzled ----
    int* idx_fin = W_sh;                   // 128
    int* wl_n    = W_sh + 128;             // 1
    int* wl_row  = W_sh + 129;             // 128
    int* wl_nc   = W_sh + 257;             // 128
    int* wl_cand = W_sh + 385;             // 128*8

    if (t == 0) wl_n[0] = 0;
    {
        int row = rg * 32 + ln;
#pragma unroll
        for (int b = 0; b < 4; ++b) {
            int s0 = ((wc * 2 + hi) * 4 + b) * 2;
            cv_sh[s0 * 128       + ((row + s0)     & 127)] = v1[b];
            ci_sh[s0 * 128       + ((row + s0)     & 127)] = i1[b];
            cv_sh[(s0 + 1) * 128 + ((row + s0 + 1) & 127)] = v2[b];
            ci_sh[(s0 + 1) * 128 + ((row + s0 + 1) & 127)] = i2[b];
        }
    }
    __syncthreads();

    if (t < BN) {
        float mv = 3.4e38f; int mi = 0x7fffffff;
#pragma unroll 8
        for (int s = 0; s < 32; ++s) {
            float v = cv_sh[s * 128 + ((t + s) & 127)];
            int  id = ci_sh[s * 128 + ((t + s) & 127)];
            if (v < mv || (v == mv && id < mi)) { mv = v; mi = id; }
        }
        int   cand[8]; int nc = 0;
        float thr = mv + MARGIN;
        for (int s = 0; s < 32; ++s) {
            float v = cv_sh[s * 128 + ((t + s) & 127)];
            int  id = ci_sh[s * 128 + ((t + s) & 127)];
            if (v <= thr && id < 1024 && nc < 8) cand[nc++] = id;
        }
        idx_fin[t] = mi;
        if (nc > 1) {
            int slot = atomicAdd(wl_n, 1);
            wl_row[slot] = t;
            wl_nc[slot]  = nc;
            for (int i = 0; i < nc; ++i) wl_cand[slot * 8 + i] = cand[i];
        }
    }
    __syncthreads();

    // ---- wave-cooperative bit-exact numpy-f32 rescore (verbatim r4) ----
    int nwl = wl_n[0];
    for (int e = w; e < nwl; e += 8) {
        int row = wl_row[e];
        int nc  = wl_nc[e];
        const float* zrow = zb + row;      // element d at zrow[d*4096]

        // a_n: np pairwise sum of z^2, 16 parallel chains (np 8-acc x 2 halves)
        int j  = l & 15, h = j >> 3, jj = j & 7;
        float x0 = zrow[(size_t)(h * 128 + jj) * 4096];
        float r  = __fmul_rn(x0, x0);
        for (int m = 1; m < 16; ++m) {
            float x = zrow[(size_t)(h * 128 + jj + 8 * m) * 4096];
            r = __fadd_rn(r, __fmul_rn(x, x));
        }
        float s1 = __fadd_rn(r,  __shfl_xor(r,  1, 64));
        float s2 = __fadd_rn(s1, __shfl_xor(s1, 2, 64));
        float s4 = __fadd_rn(s2, __shfl_xor(s2, 4, 64));
        float a_n = __fadd_rn(s4, __shfl_xor(s4, 8, 64));
        a_n = __shfl(a_n, 0, 64);

        float best = 3.4e38f; int bid = 0x7fffffff;
        for (int cx = 0; cx < nc; ++cx) {
            int id = wl_cand[e * 8 + cx];
            const float* er = emb + (size_t)id * 256;
            // b_k: same bit-exact np tree, contiguous reads
            float y0 = er[h * 128 + jj];
            float rb = __fmul_rn(y0, y0);
            for (int m = 1; m < 16; ++m) {
                float y = er[h * 128 + jj + 8 * m];
                rb = __fadd_rn(rb, __fmul_rn(y, y));
            }
            float b1 = __fadd_rn(rb, __shfl_xor(rb, 1, 64));
            float b2 = __fadd_rn(b1, __shfl_xor(b1, 2, 64));
            float b4 = __fadd_rn(b2, __shfl_xor(b2, 4, 64));
            float b_k = __fadd_rn(b4, __shfl_xor(b4, 8, 64));
            b_k = __shfl(b_k, 0, 64);
            // c: f64 dot, 64-lane butterfly (order-free, ~exact)
            double cd = 0.0;
#pragma unroll
            for (int u = 0; u < 4; ++u) {
                int d = l + u * 64;
                cd = fma((double)zrow[(size_t)d * 4096], (double)er[d], cd);
            }
#pragma unroll
            for (int off = 1; off < 64; off <<= 1) cd += __shfl_xor(cd, off, 64);
            float c32 = (float)cd;
            float sc  = __fsub_rn(__fadd_rn(a_n, b_k), __fmul_rn(2.0f, c32));
            if (sc < best || (sc == best && id < bid)) { best = sc; bid = id; }
        }
        if (l == 0) idx_fin[row] = bid;
    }
    __syncthreads();

    // ---- final index write + z_q gather (verbatim r4) ----
    if (t < BN) out[n0 + t] = (float)idx_fin[t];

    float* zq = out + 65536 + (size_t)b_img * (256 * 4096) + hw0;
    {
        int m   = t & 127;
        int sub = t >> 7;                 // 0..3
        int id  = idx_fin[m];
        const float* er = emb + (size_t)id * 256;
#pragma unroll 4
        for (int it = 0; it < 16; ++it) {
            int d4 = it * 4 + sub;        // 0..63
            f32x4 v = *(const f32x4*)&er[d4 * 4];
#pragma unroll
            for (int jj2 = 0; jj2 < 4; ++jj2)
                zq[(size_t)(d4 * 4 + jj2) * 4096 + m] = v[jj2];
        }
    }
}

// ---------------------------------------------------------------------------
extern "C" void kernel_launch(void* const* d_in, const int* in_sizes, int n_in,
                              void* d_out, int out_size, void* d_ws, size_t ws_size,
                              hipStream_t stream) {
    const float* z   = (const float*)d_in[0];   // f32 [16,256,64,64]
    const float* emb = (const float*)d_in[1];   // f32 [1024,256]
    _Float16* embf = (_Float16*)d_ws;            // 512 KB fragment-major fp16
    float* out = (float*)d_out;

    emb_prep_kernel<<<128, 256, 0, stream>>>(emb, embf);
    vq_kernel<<<65536 / BN, 512, 0, stream>>>(z, emb, embf, out);
}